// Round 13
// baseline (44.049 us; speedup 1.0000x reference)
//
#include <hip/hip_runtime.h>
#include <math.h>

#define B_ 4
#define C_ 32
#define H_ 256
#define W_ 256
#define HW_ (H_ * W_)
#define K_ 9
#define TX 32
#define TY 4
#define HX 34              // TX + 2
#define HY 6               // TY + 2
#define HCH (HX * HY)      // 204 halo positions
#define NOCT 4             // 32 channels = 4 octs of 8
#define FUH8 (NOCT * HCH)  // 816 h8 words = 12.75 KB (fu halo only)
#define EPS_ 1e-12f

typedef _Float16 h2v __attribute__((ext_vector_type(2)));
typedef _Float16 h8v __attribute__((ext_vector_type(8)));

#if defined(__has_builtin)
#if __has_builtin(__builtin_amdgcn_fdot2)
#define HAVE_FDOT2 1
#endif
#if __has_builtin(__builtin_amdgcn_cvt_pkrtz)
#define HAVE_PKRTZ 1
#endif
#endif

static __device__ __forceinline__ h2v pk2(float a, float b) {
#if defined(HAVE_PKRTZ)
    return __builtin_bit_cast(h2v, __builtin_amdgcn_cvt_pkrtz(a, b));
#else
    h2v r = {(_Float16)a, (_Float16)b};
    return r;
#endif
}

static __device__ __forceinline__ float dot2(h2v a, h2v b, float c) {
#if defined(HAVE_FDOT2)
    return __builtin_amdgcn_fdot2(a, b, c, false);
#else
    return c + (float)a[0] * (float)b[0] + (float)a[1] * (float)b[1];
#endif
}

// R12 math (h8 oct-major LDS, b128 taps, fdot2, pkrtz) on R7's block geometry:
// 256 thr, 32x4 tile, 2 thr/pixel. fu halo ONLY in LDS (12.75 KB) -> 8 blocks/CU
// (vs R12's 4): double the phase-desync granularity to break the stage/compute
// lockstep. Grid 2048 = exact 8/CU fill. fe lives in 2 h8 regs (8 VGPR) across
// the softmax -- NOT 16 fp32 (R2/R8 spill lesson); loads issued before staging
// so HBM latency hides. launch_bounds(256,8) = the ledger's proven-clean bound.
__global__ __launch_bounds__(256, 8) void asfr_kernel(const float* __restrict__ fe,
                                                      const float* __restrict__ fu,
                                                      float* __restrict__ out) {
    __shared__ h8v lds8[FUH8];    // 13056 B
    const int t = threadIdx.x;
    const int bx = blockIdx.x & 7;           // W_/TX = 8
    const int by = (blockIdx.x >> 3) & 63;   // H_/TY = 64
    const int b  = blockIdx.x >> 9;
    const int w0 = bx * TX, h0 = by * TY;

    const int x = t & 31;            // pixel x
    const int half = (t >> 5) & 1;   // channel half: octs 0-1 or 2-3
    const int y = t >> 6;            // pixel y (0..3)
    const int c0 = half << 4;
    const int pxoff = b * (C_ * HW_) + (h0 + y) * W_ + (w0 + x);

    // fe loads issued FIRST: their HBM latency hides under fu staging below.
    float fv[16];
#pragma unroll
    for (int cc = 0; cc < 16; ++cc) fv[cc] = fe[pxoff + (c0 + cc) * HW_];

    // ---- stage fu halo: unit = one h8 word (oct, pos); 816 units = 3*256 + 48
    const float* fub = fu + b * (C_ * HW_);
#pragma unroll
    for (int j = 0; j < 3; ++j) {
        int u = t + j * 256;
        int oct = u / HCH;
        int pos = u - oct * HCH;
        int r = pos / HX;
        int col = pos - r * HX;
        int hh = h0 - 1 + r;
        int ww = w0 - 1 + col;
        bool ok = ((unsigned)hh < (unsigned)H_) && ((unsigned)ww < (unsigned)W_);
        int hcl = hh < 0 ? 0 : (hh > H_ - 1 ? H_ - 1 : hh);
        int wcl = ww < 0 ? 0 : (ww > W_ - 1 ? W_ - 1 : ww);
        const float* gp = fub + (oct * 8) * HW_ + hcl * W_ + wcl;
        float v[8];
#pragma unroll
        for (int c = 0; c < 8; ++c) v[c] = gp[c * HW_];
        float m = ok ? 1.f : 0.f;
#pragma unroll
        for (int c = 0; c < 8; ++c) v[c] *= m;
        h8v hv;
#pragma unroll
        for (int c = 0; c < 4; ++c) {
            h2v p = pk2(v[2 * c], v[2 * c + 1]);
            hv[2 * c] = p[0];
            hv[2 * c + 1] = p[1];
        }
        lds8[u] = hv;
    }
    if (t < FUH8 - 768) {   // tail 48
        int u = t + 768;
        int oct = u / HCH;
        int pos = u - oct * HCH;
        int r = pos / HX;
        int col = pos - r * HX;
        int hh = h0 - 1 + r;
        int ww = w0 - 1 + col;
        bool ok = ((unsigned)hh < (unsigned)H_) && ((unsigned)ww < (unsigned)W_);
        int hcl = hh < 0 ? 0 : (hh > H_ - 1 ? H_ - 1 : hh);
        int wcl = ww < 0 ? 0 : (ww > W_ - 1 ? W_ - 1 : ww);
        const float* gp = fub + (oct * 8) * HW_ + hcl * W_ + wcl;
        float v[8];
#pragma unroll
        for (int c = 0; c < 8; ++c) v[c] = gp[c * HW_];
        float m = ok ? 1.f : 0.f;
#pragma unroll
        for (int c = 0; c < 8; ++c) v[c] *= m;
        h8v hv;
#pragma unroll
        for (int c = 0; c < 4; ++c) {
            h2v p = pk2(v[2 * c], v[2 * c + 1]);
            hv[2 * c] = p[0];
            hv[2 * c + 1] = p[1];
        }
        lds8[u] = hv;
    }

    // convert fe to 2 x h8 (the only state besides stats crossing the softmax)
    h8v fe8[2];
#pragma unroll
    for (int j = 0; j < 2; ++j) {
#pragma unroll
        for (int c = 0; c < 4; ++c) {
            h2v p = pk2(fv[8 * j + 2 * c], fv[8 * j + 2 * c + 1]);
            fe8[j][2 * c] = p[0];
            fe8[j][2 * c + 1] = p[1];
        }
    }
    __syncthreads();

    const int hc = (y + 1) * HX + (x + 1);
    const int koff[K_] = {-HX - 1, -HX, -HX + 1, -1, 0, 1, HX - 1, HX, HX + 1};

    float dot[K_], psq[K_];
#pragma unroll
    for (int k = 0; k < K_; ++k) { dot[k] = 0.f; psq[k] = 0.f; }
    float fsq = 0.f;

    // Pass 1: per-k stats over this half's 2 octs; b128 taps, fdot2 f32-accum
#pragma unroll
    for (int j = 0; j < 2; ++j) {
        const int oct = 2 * half + j;
        h8v fq = fe8[j];
        h2v fA0 = __builtin_shufflevector(fq, fq, 0, 1);
        h2v fA1 = __builtin_shufflevector(fq, fq, 2, 3);
        h2v fA2 = __builtin_shufflevector(fq, fq, 4, 5);
        h2v fA3 = __builtin_shufflevector(fq, fq, 6, 7);
        fsq = dot2(fA0, fA0, fsq);
        fsq = dot2(fA1, fA1, fsq);
        fsq = dot2(fA2, fA2, fsq);
        fsq = dot2(fA3, fA3, fsq);
        const h8v* fubase = &lds8[oct * HCH + hc];
#pragma unroll
        for (int k = 0; k < K_; ++k) {
            h8v p8 = fubase[koff[k]];
            h2v p0 = __builtin_shufflevector(p8, p8, 0, 1);
            h2v p1 = __builtin_shufflevector(p8, p8, 2, 3);
            h2v p2 = __builtin_shufflevector(p8, p8, 4, 5);
            h2v p3 = __builtin_shufflevector(p8, p8, 6, 7);
            dot[k] = dot2(p0, fA0, dot[k]);
            dot[k] = dot2(p1, fA1, dot[k]);
            dot[k] = dot2(p2, fA2, dot[k]);
            dot[k] = dot2(p3, fA3, dot[k]);
            psq[k] = dot2(p0, p0, psq[k]);
            psq[k] = dot2(p1, p1, psq[k]);
            psq[k] = dot2(p2, p2, psq[k]);
            psq[k] = dot2(p3, p3, psq[k]);
        }
    }

    // combine halves: lanes l and l^32 hold the two channel-halves of one pixel
#pragma unroll
    for (int k = 0; k < K_; ++k) {
        dot[k] += __shfl_xor(dot[k], 32);
        psq[k] += __shfl_xor(psq[k], 32);
    }
    fsq += __shfl_xor(fsq, 32);

    float nf = fmaxf(sqrtf(fsq), EPS_);
    float cosv[K_], negd[K_];
#pragma unroll
    for (int k = 0; k < K_; ++k) {
        float np = fmaxf(sqrtf(psq[k]), EPS_);
        cosv[k] = __fdividef(dot[k], np * nf);
        float dsq = fmaxf(psq[k] - 2.f * dot[k] + fsq, 0.f);   // ||p-f||^2
        negd[k] = -sqrtf(dsq);
    }

    float m1 = cosv[0], m2 = negd[0];
#pragma unroll
    for (int k = 1; k < K_; ++k) { m1 = fmaxf(m1, cosv[k]); m2 = fmaxf(m2, negd[k]); }
    float s1 = 0.f, s2 = 0.f, e1[K_], e2[K_];
#pragma unroll
    for (int k = 0; k < K_; ++k) {
        e1[k] = __expf(cosv[k] - m1);
        e2[k] = __expf(negd[k] - m2);
        s1 += e1[k]; s2 += e2[k];
    }
    float r1 = __fdividef(0.5f, s1), r2 = __fdividef(0.5f, s2);
    h2v w2[K_];
#pragma unroll
    for (int k = 0; k < K_; ++k) {
        float wk = fmaf(e1[k], r1, e2[k] * r2);
        _Float16 wh = (_Float16)wk;
        h2v tmp = {wh, wh};
        w2[k] = tmp;
    }

    // Pass 2: packed weighted gather (b128 taps) + f16 residual from regs
#pragma unroll
    for (int j = 0; j < 2; ++j) {
        const int oct = 2 * half + j;
        const h8v* fubase = &lds8[oct * HCH + hc];
        h2v a0 = {(_Float16)0, (_Float16)0};
        h2v a1 = a0, a2 = a0, a3 = a0;
#pragma unroll
        for (int k = 0; k < K_; ++k) {
            h8v p8 = fubase[koff[k]];
            a0 += w2[k] * __builtin_shufflevector(p8, p8, 0, 1);
            a1 += w2[k] * __builtin_shufflevector(p8, p8, 2, 3);
            a2 += w2[k] * __builtin_shufflevector(p8, p8, 4, 5);
            a3 += w2[k] * __builtin_shufflevector(p8, p8, 6, 7);
        }
        h8v fq = fe8[j];
        const int cg = oct * 8;
        out[pxoff + (cg + 0) * HW_] = (float)(fq[0] + a0[0]);
        out[pxoff + (cg + 1) * HW_] = (float)(fq[1] + a0[1]);
        out[pxoff + (cg + 2) * HW_] = (float)(fq[2] + a1[0]);
        out[pxoff + (cg + 3) * HW_] = (float)(fq[3] + a1[1]);
        out[pxoff + (cg + 4) * HW_] = (float)(fq[4] + a2[0]);
        out[pxoff + (cg + 5) * HW_] = (float)(fq[5] + a2[1]);
        out[pxoff + (cg + 6) * HW_] = (float)(fq[6] + a3[0]);
        out[pxoff + (cg + 7) * HW_] = (float)(fq[7] + a3[1]);
    }
}

extern "C" void kernel_launch(void* const* d_in, const int* in_sizes, int n_in,
                              void* d_out, int out_size, void* d_ws, size_t ws_size,
                              hipStream_t stream) {
    const float* fe = (const float*)d_in[0];
    const float* fu = (const float*)d_in[1];
    float* out = (float*)d_out;
    dim3 grid((W_ / TX) * (H_ / TY) * B_), block(256);  // 2048 blocks = 8/CU exact
    hipLaunchKernelGGL(asfr_kernel, grid, block, 0, stream, fe, fu, out);
}

// Round 14
// 33.279 us; speedup vs baseline: 1.3236x; 1.3236x over previous
//
#include <hip/hip_runtime.h>
#include <math.h>

#define B_ 4
#define C_ 32
#define H_ 256
#define W_ 256
#define HW_ (H_ * W_)
#define K_ 9
#define TX 32
#define TY 4
#define HX 34              // TX + 2
#define HY 6               // TY + 2
#define HCH (HX * HY)      // 204 halo positions
#define NOCT 4             // 32 channels = 4 octs of 8
#define FUH8 (NOCT * HCH)  // 816 h8 words = 12.75 KB (fu halo only)
#define EPS_ 1e-12f

typedef _Float16 h2v __attribute__((ext_vector_type(2)));
typedef _Float16 h8v __attribute__((ext_vector_type(8)));

#if defined(__has_builtin)
#if __has_builtin(__builtin_amdgcn_fdot2)
#define HAVE_FDOT2 1
#endif
#if __has_builtin(__builtin_amdgcn_cvt_pkrtz)
#define HAVE_PKRTZ 1
#endif
#endif

static __device__ __forceinline__ h2v pk2(float a, float b) {
#if defined(HAVE_PKRTZ)
    return __builtin_bit_cast(h2v, __builtin_amdgcn_cvt_pkrtz(a, b));
#else
    h2v r = {(_Float16)a, (_Float16)b};
    return r;
#endif
}

static __device__ __forceinline__ float dot2(h2v a, h2v b, float c) {
#if defined(HAVE_FDOT2)
    return __builtin_amdgcn_fdot2(a, b, c, false);
#else
    return c + (float)a[0] * (float)b[0] + (float)a[1] * (float)b[1];
#endif
}

// R13 structure, launch-bounds fix. EMPIRICAL VGPR-cap ledger on this harness:
// (256,8)->cap 32 (R6/R7 clean because live<=32; R8/R13 SPILLED at live 49-60),
// (512,4)->cap>=60 clean, (256,6)->cap~85 clean (R4, VGPR 40), (256,3)/(512,8)/
// (1024,8)->spill. Live set here ~49 (fe8 8 + stats 19 + softmax temps ~22) ->
// needs cap >=64 -> (256,6). If allocator lands <=64 VGPR, 8 blocks/CU still
// fit (8 waves/SIMD x 64 = 512-reg pool), giving the desync vs R12's 4/CU.
__global__ __launch_bounds__(256, 6) void asfr_kernel(const float* __restrict__ fe,
                                                      const float* __restrict__ fu,
                                                      float* __restrict__ out) {
    __shared__ h8v lds8[FUH8];    // 13056 B
    const int t = threadIdx.x;
    const int bx = blockIdx.x & 7;           // W_/TX = 8
    const int by = (blockIdx.x >> 3) & 63;   // H_/TY = 64
    const int b  = blockIdx.x >> 9;
    const int w0 = bx * TX, h0 = by * TY;

    const int x = t & 31;            // pixel x
    const int half = (t >> 5) & 1;   // channel half: octs 0-1 or 2-3
    const int y = t >> 6;            // pixel y (0..3)
    const int c0 = half << 4;
    const int pxoff = b * (C_ * HW_) + (h0 + y) * W_ + (w0 + x);

    // fe loads issued FIRST: their HBM latency hides under fu staging below.
    float fv[16];
#pragma unroll
    for (int cc = 0; cc < 16; ++cc) fv[cc] = fe[pxoff + (c0 + cc) * HW_];

    // ---- stage fu halo: unit = one h8 word (oct, pos); 816 units = 3*256 + 48
    const float* fub = fu + b * (C_ * HW_);
#pragma unroll
    for (int j = 0; j < 3; ++j) {
        int u = t + j * 256;
        int oct = u / HCH;
        int pos = u - oct * HCH;
        int r = pos / HX;
        int col = pos - r * HX;
        int hh = h0 - 1 + r;
        int ww = w0 - 1 + col;
        bool ok = ((unsigned)hh < (unsigned)H_) && ((unsigned)ww < (unsigned)W_);
        int hcl = hh < 0 ? 0 : (hh > H_ - 1 ? H_ - 1 : hh);
        int wcl = ww < 0 ? 0 : (ww > W_ - 1 ? W_ - 1 : ww);
        const float* gp = fub + (oct * 8) * HW_ + hcl * W_ + wcl;
        float v[8];
#pragma unroll
        for (int c = 0; c < 8; ++c) v[c] = gp[c * HW_];
        float m = ok ? 1.f : 0.f;
#pragma unroll
        for (int c = 0; c < 8; ++c) v[c] *= m;
        h8v hv;
#pragma unroll
        for (int c = 0; c < 4; ++c) {
            h2v p = pk2(v[2 * c], v[2 * c + 1]);
            hv[2 * c] = p[0];
            hv[2 * c + 1] = p[1];
        }
        lds8[u] = hv;
    }
    if (t < FUH8 - 768) {   // tail 48
        int u = t + 768;
        int oct = u / HCH;
        int pos = u - oct * HCH;
        int r = pos / HX;
        int col = pos - r * HX;
        int hh = h0 - 1 + r;
        int ww = w0 - 1 + col;
        bool ok = ((unsigned)hh < (unsigned)H_) && ((unsigned)ww < (unsigned)W_);
        int hcl = hh < 0 ? 0 : (hh > H_ - 1 ? H_ - 1 : hh);
        int wcl = ww < 0 ? 0 : (ww > W_ - 1 ? W_ - 1 : ww);
        const float* gp = fub + (oct * 8) * HW_ + hcl * W_ + wcl;
        float v[8];
#pragma unroll
        for (int c = 0; c < 8; ++c) v[c] = gp[c * HW_];
        float m = ok ? 1.f : 0.f;
#pragma unroll
        for (int c = 0; c < 8; ++c) v[c] *= m;
        h8v hv;
#pragma unroll
        for (int c = 0; c < 4; ++c) {
            h2v p = pk2(v[2 * c], v[2 * c + 1]);
            hv[2 * c] = p[0];
            hv[2 * c + 1] = p[1];
        }
        lds8[u] = hv;
    }

    // convert fe to 2 x h8 (the only state besides stats crossing the softmax)
    h8v fe8[2];
#pragma unroll
    for (int j = 0; j < 2; ++j) {
#pragma unroll
        for (int c = 0; c < 4; ++c) {
            h2v p = pk2(fv[8 * j + 2 * c], fv[8 * j + 2 * c + 1]);
            fe8[j][2 * c] = p[0];
            fe8[j][2 * c + 1] = p[1];
        }
    }
    __syncthreads();

    const int hc = (y + 1) * HX + (x + 1);
    const int koff[K_] = {-HX - 1, -HX, -HX + 1, -1, 0, 1, HX - 1, HX, HX + 1};

    float dot[K_], psq[K_];
#pragma unroll
    for (int k = 0; k < K_; ++k) { dot[k] = 0.f; psq[k] = 0.f; }
    float fsq = 0.f;

    // Pass 1: per-k stats over this half's 2 octs; b128 taps, fdot2 f32-accum
#pragma unroll
    for (int j = 0; j < 2; ++j) {
        const int oct = 2 * half + j;
        h8v fq = fe8[j];
        h2v fA0 = __builtin_shufflevector(fq, fq, 0, 1);
        h2v fA1 = __builtin_shufflevector(fq, fq, 2, 3);
        h2v fA2 = __builtin_shufflevector(fq, fq, 4, 5);
        h2v fA3 = __builtin_shufflevector(fq, fq, 6, 7);
        fsq = dot2(fA0, fA0, fsq);
        fsq = dot2(fA1, fA1, fsq);
        fsq = dot2(fA2, fA2, fsq);
        fsq = dot2(fA3, fA3, fsq);
        const h8v* fubase = &lds8[oct * HCH + hc];
#pragma unroll
        for (int k = 0; k < K_; ++k) {
            h8v p8 = fubase[koff[k]];
            h2v p0 = __builtin_shufflevector(p8, p8, 0, 1);
            h2v p1 = __builtin_shufflevector(p8, p8, 2, 3);
            h2v p2 = __builtin_shufflevector(p8, p8, 4, 5);
            h2v p3 = __builtin_shufflevector(p8, p8, 6, 7);
            dot[k] = dot2(p0, fA0, dot[k]);
            dot[k] = dot2(p1, fA1, dot[k]);
            dot[k] = dot2(p2, fA2, dot[k]);
            dot[k] = dot2(p3, fA3, dot[k]);
            psq[k] = dot2(p0, p0, psq[k]);
            psq[k] = dot2(p1, p1, psq[k]);
            psq[k] = dot2(p2, p2, psq[k]);
            psq[k] = dot2(p3, p3, psq[k]);
        }
    }

    // combine halves: lanes l and l^32 hold the two channel-halves of one pixel
#pragma unroll
    for (int k = 0; k < K_; ++k) {
        dot[k] += __shfl_xor(dot[k], 32);
        psq[k] += __shfl_xor(psq[k], 32);
    }
    fsq += __shfl_xor(fsq, 32);

    float nf = fmaxf(sqrtf(fsq), EPS_);
    float cosv[K_], negd[K_];
#pragma unroll
    for (int k = 0; k < K_; ++k) {
        float np = fmaxf(sqrtf(psq[k]), EPS_);
        cosv[k] = __fdividef(dot[k], np * nf);
        float dsq = fmaxf(psq[k] - 2.f * dot[k] + fsq, 0.f);   // ||p-f||^2
        negd[k] = -sqrtf(dsq);
    }

    float m1 = cosv[0], m2 = negd[0];
#pragma unroll
    for (int k = 1; k < K_; ++k) { m1 = fmaxf(m1, cosv[k]); m2 = fmaxf(m2, negd[k]); }
    float s1 = 0.f, s2 = 0.f, e1[K_], e2[K_];
#pragma unroll
    for (int k = 0; k < K_; ++k) {
        e1[k] = __expf(cosv[k] - m1);
        e2[k] = __expf(negd[k] - m2);
        s1 += e1[k]; s2 += e2[k];
    }
    float r1 = __fdividef(0.5f, s1), r2 = __fdividef(0.5f, s2);
    h2v w2[K_];
#pragma unroll
    for (int k = 0; k < K_; ++k) {
        float wk = fmaf(e1[k], r1, e2[k] * r2);
        _Float16 wh = (_Float16)wk;
        h2v tmp = {wh, wh};
        w2[k] = tmp;
    }

    // Pass 2: packed weighted gather (b128 taps) + f16 residual from regs
#pragma unroll
    for (int j = 0; j < 2; ++j) {
        const int oct = 2 * half + j;
        const h8v* fubase = &lds8[oct * HCH + hc];
        h2v a0 = {(_Float16)0, (_Float16)0};
        h2v a1 = a0, a2 = a0, a3 = a0;
#pragma unroll
        for (int k = 0; k < K_; ++k) {
            h8v p8 = fubase[koff[k]];
            a0 += w2[k] * __builtin_shufflevector(p8, p8, 0, 1);
            a1 += w2[k] * __builtin_shufflevector(p8, p8, 2, 3);
            a2 += w2[k] * __builtin_shufflevector(p8, p8, 4, 5);
            a3 += w2[k] * __builtin_shufflevector(p8, p8, 6, 7);
        }
        h8v fq = fe8[j];
        const int cg = oct * 8;
        out[pxoff + (cg + 0) * HW_] = (float)(fq[0] + a0[0]);
        out[pxoff + (cg + 1) * HW_] = (float)(fq[1] + a0[1]);
        out[pxoff + (cg + 2) * HW_] = (float)(fq[2] + a1[0]);
        out[pxoff + (cg + 3) * HW_] = (float)(fq[3] + a1[1]);
        out[pxoff + (cg + 4) * HW_] = (float)(fq[4] + a2[0]);
        out[pxoff + (cg + 5) * HW_] = (float)(fq[5] + a2[1]);
        out[pxoff + (cg + 6) * HW_] = (float)(fq[6] + a3[0]);
        out[pxoff + (cg + 7) * HW_] = (float)(fq[7] + a3[1]);
    }
}

extern "C" void kernel_launch(void* const* d_in, const int* in_sizes, int n_in,
                              void* d_out, int out_size, void* d_ws, size_t ws_size,
                              hipStream_t stream) {
    const float* fe = (const float*)d_in[0];
    const float* fu = (const float*)d_in[1];
    float* out = (float*)d_out;
    dim3 grid((W_ / TX) * (H_ / TY) * B_), block(256);  // 2048 blocks
    hipLaunchKernelGGL(asfr_kernel, grid, block, 0, stream, fe, fu, out);
}